// Round 1
// 383.227 us; speedup vs baseline: 1.0371x; 1.0371x over previous
//
#include <hip/hip_runtime.h>
#include <hip/hip_bf16.h>

#define NN 50000
#define EE 1600000
#define NT_N 391        // ceil(NN/128) node tiles
#define NIV 129         // piecewise-linear intervals (<=128 breakpoints + 1)

typedef float f32x4 __attribute__((ext_vector_type(4)));
typedef __bf16 bf16x8 __attribute__((ext_vector_type(8)));

// Piecewise-linear tables for the edge MLP (input is a SCALAR length):
//   out[c] = len * gA[iv][c] + gB[iv][c],  iv = #{ sorted breakpoints < len }
__device__ float gT[128];                       // sorted breakpoints
__device__ int   gRank[128];                    // rank of unit k's breakpoint
__device__ __align__(16) float gA[NIV * 128];
__device__ __align__(16) float gB[NIV * 128];

__device__ __forceinline__ float edge_len(int e, const int* __restrict__ eidx,
                                          const float* __restrict__ pos,
                                          const float* __restrict__ lp,
                                          const int* __restrict__ msk) {
    int ri = eidx[e];
    int ci = eidx[EE + e];
    const float* pr = msk[ri] ? lp : pos;
    const float* pc = msk[ci] ? lp : pos;
    float dx = pr[3 * ri + 0] - pc[3 * ci + 0];
    float dy = pr[3 * ri + 1] - pc[3 * ci + 1];
    float dz = pr[3 * ri + 2] - pc[3 * ci + 2];
    return sqrtf(dx * dx + dy * dy + dz * dz);
}

// ---- prep1: breakpoints + ranks (1 block, 128 threads) -------------------
// t_k = -b1[k]/W1[k]; W1[k]==0 never toggles -> t=+inf (sorts last, never < len).
// Strict total order (t, k) -> ranks are a permutation.
__global__ void prep1(const float* __restrict__ Wd1, const float* __restrict__ bd1) {
    int k = threadIdx.x;
    float w1 = Wd1[k], b1 = bd1[k];
    float t = (w1 == 0.f) ? __builtin_inff() : (-b1 / w1);
    int rank = 0;
    for (int j = 0; j < 128; j++) {
        float w1j = Wd1[j], b1j = bd1[j];
        float tj = (w1j == 0.f) ? __builtin_inff() : (-b1j / w1j);
        rank += (tj < t) || (tj == t && j < k);
    }
    gRank[k] = rank;
    gT[rank] = t;
}

// ---- prep2: per-interval linear coefficients (129 blocks x 128 threads) --
// Interval i = (t_sorted[i-1], t_sorted[i]). Unit k active there iff
//   W1[k]>0: rank_k < i;  W1[k]<0: rank_k >= i;  W1[k]==0: b1[k]>0.
// Continuity of the PWL function makes boundary/tie choices immaterial.
__global__ void prep2(const float* __restrict__ Wd1, const float* __restrict__ bd1,
                      const float* __restrict__ Wd2, const float* __restrict__ bd2) {
    int i = blockIdx.x;      // interval
    int c = threadIdx.x;     // output channel
    float a = 0.f, b = 0.f;
    for (int k = 0; k < 128; k++) {
        float w1 = Wd1[k], b1 = bd1[k];
        bool act = (w1 > 0.f) ? (gRank[k] < i)
                 : (w1 < 0.f) ? (gRank[k] >= i)
                              : (b1 > 0.f);
        if (act) {
            float w2 = Wd2[k * 128 + c];
            a = fmaf(w1, w2, a);
            b = fmaf(b1, w2, b);
        }
    }
    gA[i * 128 + c] = a;
    gB[i * 128 + c] = b + bd2[c];
}

// ---- phase 1: gather-only edge lengths (unchanged) -----------------------
__global__ __launch_bounds__(256) void len_kernel(
    const int* __restrict__ eidx, const float* __restrict__ pos,
    const float* __restrict__ lp, const int* __restrict__ msk,
    float* __restrict__ len)
{
    int e = blockIdx.x * 256 + threadIdx.x;
    if (e < EE) len[e] = edge_len(e, eidx, pos, lp, msk);
}

// ---- edge kernel: pure stream, no MFMA/barriers/transpose ----------------
// 32 lanes per row (f32x4 channels); 8 rows per 256-thread block per iter.
// Binary search is branchless, 8 steps over gT in LDS (broadcast reads).
// With the bench data all breakpoints coincide -> one interval -> A/B rows L1-hot.
template <bool PRECOMP>
__global__ __launch_bounds__(256) void edge_kernel(
    const float* __restrict__ ea, const float* __restrict__ len,
    const int* __restrict__ eidx, const float* __restrict__ pos,
    const float* __restrict__ lp, const int* __restrict__ msk,
    float* __restrict__ oute)
{
    __shared__ float ts[128];
    if (threadIdx.x < 128) ts[threadIdx.x] = gT[threadIdx.x];
    __syncthreads();

    const int g  = threadIdx.x >> 5;          // row group within block
    const int c4 = (threadIdx.x & 31) * 4;    // channel base

    for (int r = blockIdx.x * 8 + g; r < EE; r += gridDim.x * 8) {
        float lv = PRECOMP ? len[r] : edge_len(r, eidx, pos, lp, msk);

        // iv = #{ ts[j] < lv }, ts sorted ascending, result in [0,128]
        int lo = 0;
#pragma unroll
        for (int s = 128; s > 0; s >>= 1) {
            int m = lo + s;
            if (m <= 128 && ts[m - 1] < lv) lo = m;
        }

        const f32x4 a = *(const f32x4*)&gA[lo * 128 + c4];
        const f32x4 b = *(const f32x4*)&gB[lo * 128 + c4];
        const size_t off = (size_t)r * 128 + c4;
        f32x4 e = __builtin_nontemporal_load((const f32x4*)(ea + off));
        f32x4 o = e + (lv * a + b);
        __builtin_nontemporal_store(o, (f32x4*)(oute + off));
    }
}

// ---- node path: proven MFMA + LDS-transpose structure, node tiles only ---
// W2 LDS layout (bf16): dst = (((k>>5)*8 + (c>>4))*64 + (((k>>3)&3)*16 + (c&15)))*8 + (k&7)
__device__ __forceinline__ void stage_w2(const float* __restrict__ W2, __bf16* w2l) {
    for (int idx = threadIdx.x; idx < 128 * 128; idx += 512) {
        int k = idx >> 7;
        int c = idx & 127;
        int dst = (((k >> 5) * 8 + (c >> 4)) * 64 + (((k >> 3) & 3) * 16 + (c & 15))) * 8 + (k & 7);
        w2l[dst] = (__bf16)W2[idx];
    }
}

// Barriers are block-uniform: the node-tail wave predicate is a `valid` flag,
// never a `continue`. __syncthreads() on both sides of the transpose read is
// REQUIRED (lane-crossing through LDS has no per-thread dependence edge).
__global__ __launch_bounds__(512, 3) void node_kernel(
    const float* __restrict__ pos, const float* __restrict__ x,
    const float* __restrict__ lp, const int* __restrict__ msk,
    const float* __restrict__ Wp1, const float* __restrict__ bp1,
    const float* __restrict__ Wp2, const float* __restrict__ bp2,
    float* __restrict__ outx)
{
    __shared__ __bf16 w2l[16384];
    __shared__ float w1l[384], b1l[128], b2l[128];
    __shared__ float tbuf[8][512];   // per-wave 2 KB transpose buffer

    stage_w2(Wp2, w2l);
    for (int i = threadIdx.x; i < 384; i += 512) w1l[i] = Wp1[i];
    if (threadIdx.x < 128) {
        b1l[threadIdx.x] = bp1[threadIdx.x];
        b2l[threadIdx.x] = bp2[threadIdx.x];
    }
    __syncthreads();

    const int w = threadIdx.x >> 6;
    const int l = threadIdx.x & 63;
    const int llo = l & 15;
    const int lgrp = l >> 4;
    float* tb = tbuf[w];

    const int base = blockIdx.x * 128;
    const int e0 = base + w * 16;
    // NN % 16 == 0 -> node validity is all-or-nothing per wave.
    const bool valid = (e0 + 16 <= NN);

    f32x4 ear[8];
    f32x4 acc[8];
    if (valid) {
        const float* srow = x + (size_t)e0 * 128;
#pragma unroll
        for (int j = 0; j < 8; j++) ear[j] = *(const f32x4*)(srow + j * 256 + l * 4);

        int nd = e0 + llo;
        const float* p = msk[nd] ? lp : pos;
        float px = p[3 * nd + 0];
        float py = p[3 * nd + 1];
        float pz = p[3 * nd + 2];

#pragma unroll
        for (int m = 0; m < 8; m++) acc[m] = (f32x4){0.f, 0.f, 0.f, 0.f};

#pragma unroll
        for (int kk = 0; kk < 4; kk++) {
            bf16x8 hf;
#pragma unroll
            for (int j = 0; j < 8; j++) {
                int k = kk * 32 + lgrp * 8 + j;
                float h = px * w1l[k] + py * w1l[128 + k] + pz * w1l[256 + k] + b1l[k];
                hf[j] = (__bf16)fmaxf(h, 0.f);
            }
#pragma unroll
            for (int m = 0; m < 8; m++) {
                bf16x8 wf = *(const bf16x8*)&w2l[((kk * 8 + m) * 64 + l) * 8];
                acc[m] = __builtin_amdgcn_mfma_f32_16x16x32_bf16(wf, hf, acc[m], 0, 0, 0);
            }
        }
    }

    float* drow = outx + (size_t)e0 * 128;
    f32x4 b2v = *(const f32x4*)&b2l[(l & 31) * 4];

#pragma unroll
    for (int p = 0; p < 4; p++) {
        if (valid && (llo >> 2) == p) {
            int r = llo & 3;
#pragma unroll
            for (int m = 0; m < 8; m++) {
                int c = (m * 16 + lgrp * 4 + r * 4) & 127;   // rotate row r by r*4 floats
                *(f32x4*)&tb[r * 128 + c] = acc[m];
            }
        }
        __syncthreads();   // RAW: other lanes' writes -> this lane's reads
        if (valid) {
#pragma unroll
            for (int i = 0; i < 2; i++) {
                int row = 2 * i + (l >> 5);
                int c = ((l & 31) * 4 + row * 4) & 127;
                f32x4 tv = *(const f32x4*)&tb[row * 128 + c];
                f32x4 o = tv + b2v + ear[p * 2 + i];
                *(f32x4*)(drow + p * 512 + i * 256 + l * 4) = o;
            }
        }
        __syncthreads();   // WAR: reads done before next pass overwrites tb
    }
}

extern "C" void kernel_launch(void* const* d_in, const int* in_sizes, int n_in,
                              void* d_out, int out_size, void* d_ws, size_t ws_size,
                              hipStream_t stream) {
    const float* pos        = (const float*)d_in[0];
    const float* x          = (const float*)d_in[1];
    const float* edge_attr  = (const float*)d_in[2];
    const int* edge_index   = (const int*)d_in[3];
    const float* last_pred  = (const float*)d_in[4];
    const int* mask         = (const int*)d_in[5];
    const float* Wp1 = (const float*)d_in[6];
    const float* bp1 = (const float*)d_in[7];
    const float* Wp2 = (const float*)d_in[8];
    const float* bp2 = (const float*)d_in[9];
    const float* Wd1 = (const float*)d_in[10];
    const float* bd1 = (const float*)d_in[11];
    const float* Wd2 = (const float*)d_in[12];
    const float* bd2 = (const float*)d_in[13];

    float* outx = (float*)d_out;                    // [N,128]
    float* oute = outx + (size_t)NN * 128;          // [E,128]
    float* len  = (float*)d_ws;                     // [E]

    // Build the piecewise-linear tables for the scalar-input edge MLP.
    prep1<<<1, 128, 0, stream>>>(Wd1, bd1);
    prep2<<<NIV, 128, 0, stream>>>(Wd1, bd1, Wd2, bd2);

    // Node path (3% of traffic): MFMA structure, 391 tiles.
    node_kernel<<<NT_N, 512, 0, stream>>>(pos, x, last_pred, mask,
                                          Wp1, bp1, Wp2, bp2, outx);

    if (ws_size >= (size_t)EE * sizeof(float)) {
        len_kernel<<<(EE + 255) / 256, 256, 0, stream>>>(edge_index, pos, last_pred, mask, len);
        edge_kernel<true><<<2048, 256, 0, stream>>>(edge_attr, len, edge_index,
                                                    pos, last_pred, mask, oute);
    } else {
        edge_kernel<false><<<2048, 256, 0, stream>>>(edge_attr, nullptr, edge_index,
                                                     pos, last_pred, mask, oute);
    }
}